// Round 1
// baseline (534.563 us; speedup 1.0000x reference)
//
#include <hip/hip_runtime.h>

// XSReLU percentile: per-row exact 80th-percentile cutoff + relu(x - cutoff).
// Input: (B=1024, N=65536) fp32. One workgroup per row.
// Exact selection via 12-bit LDS histogram -> candidate gather -> 20-bit
// in-LDS radix select. Then elementwise relu pass.

#define TPB   512
#define NBINS 4096   // top 12 bits of order-preserving uint
#define CAP   6144   // candidate buffer (expected ~1.1k for N(0,1) rows)

__device__ __forceinline__ unsigned f2ord(float f) {
    unsigned u = __float_as_uint(f);
    // monotone map: negative floats -> [0, 2^31), positive -> [2^31, 2^32)
    return (u & 0x80000000u) ? ~u : (u | 0x80000000u);
}
__device__ __forceinline__ float ord2f(unsigned u) {
    unsigned b = (u & 0x80000000u) ? (u ^ 0x80000000u) : ~u;
    return __uint_as_float(b);
}

__global__ __launch_bounds__(TPB)
void xsrelu_perc_kernel(const float* __restrict__ in, float* __restrict__ out,
                        int N, int k) {
    const int row = blockIdx.x;
    const int tid = threadIdx.x;
    const float4* __restrict__ rowv = (const float4*)(in + (size_t)row * (size_t)N);
    float4* __restrict__ outv = (float4*)(out + (size_t)row * (size_t)N);
    const int nv = N >> 2;

    __shared__ unsigned hist[NBINS];
    __shared__ unsigned cand[CAP];
    __shared__ unsigned part[TPB];
    __shared__ unsigned scan[TPB];
    __shared__ unsigned s_bin, s_cum, s_cnt;
    __shared__ float    s_cut;

    for (int i = tid; i < NBINS; i += TPB) hist[i] = 0u;
    if (tid == 0) s_cnt = 0u;
    __syncthreads();

    // ---- Pass A: 12-bit histogram (float4 loads, LDS atomics) ----
    for (int i = tid; i < nv; i += TPB) {
        float4 v = rowv[i];
        atomicAdd(&hist[f2ord(v.x) >> 20], 1u);
        atomicAdd(&hist[f2ord(v.y) >> 20], 1u);
        atomicAdd(&hist[f2ord(v.z) >> 20], 1u);
        atomicAdd(&hist[f2ord(v.w) >> 20], 1u);
    }
    __syncthreads();

    // ---- find target bin: per-thread 8-bin sums + block inclusive scan ----
    const int BPT = NBINS / TPB;   // 8 bins per thread
    const int base = tid * BPT;
    unsigned s = 0;
    #pragma unroll
    for (int j = 0; j < BPT; ++j) s += hist[base + j];
    part[tid] = s;
    scan[tid] = s;
    __syncthreads();
    for (int off = 1; off < TPB; off <<= 1) {
        unsigned add = (tid >= off) ? scan[tid - off] : 0u;
        __syncthreads();
        scan[tid] += add;
        __syncthreads();
    }
    const unsigned r = (unsigned)k;          // 0-based rank in the row
    {
        unsigned incl = scan[tid];
        unsigned excl = incl - part[tid];
        if (r >= excl && r < incl) {         // exactly one thread qualifies
            unsigned c = excl;
            #pragma unroll
            for (int j = 0; j < BPT; ++j) {
                unsigned h = hist[base + j];
                if (r < c + h) { s_bin = (unsigned)(base + j); s_cum = c; break; }
                c += h;
            }
        }
    }
    __syncthreads();
    const unsigned bin = s_bin;

    // ---- Pass B: gather candidates in the target bin ----
    for (int i = tid; i < nv; i += TPB) {
        float4 v = rowv[i];
        unsigned u0 = f2ord(v.x), u1 = f2ord(v.y), u2 = f2ord(v.z), u3 = f2ord(v.w);
        if ((u0 >> 20) == bin) { unsigned p = atomicAdd(&s_cnt, 1u); if (p < CAP) cand[p] = u0; }
        if ((u1 >> 20) == bin) { unsigned p = atomicAdd(&s_cnt, 1u); if (p < CAP) cand[p] = u1; }
        if ((u2 >> 20) == bin) { unsigned p = atomicAdd(&s_cnt, 1u); if (p < CAP) cand[p] = u2; }
        if ((u3 >> 20) == bin) { unsigned p = atomicAdd(&s_cnt, 1u); if (p < CAP) cand[p] = u3; }
    }
    __syncthreads();

    // ---- bitwise radix select of remaining 20 bits, wave 0 only ----
    if (tid < 64) {
        unsigned M = s_cnt; if (M > CAP) M = CAP;
        unsigned prefix = bin;          // 12 known top bits
        unsigned r2 = r - s_cum;        // rank among candidates
        for (int bit = 19; bit >= 0; --bit) {
            const unsigned want0 = prefix << 1;   // prefix extended with 0
            unsigned cnt = 0;
            for (unsigned i = (unsigned)tid; i < M; i += 64u)
                if ((cand[i] >> bit) == want0) cnt++;
            #pragma unroll
            for (int o = 32; o > 0; o >>= 1) cnt += __shfl_down(cnt, o);
            cnt = __shfl(cnt, 0);                 // broadcast wave total
            if (r2 < cnt) { prefix = want0; }
            else          { r2 -= cnt; prefix = want0 | 1u; }
        }
        if (tid == 0) s_cut = ord2f(prefix);
    }
    __syncthreads();
    const float cut = s_cut;

    // ---- Pass C: relu(x - cutoff), float4 stores ----
    for (int i = tid; i < nv; i += TPB) {
        float4 v = rowv[i];
        float4 o;
        o.x = fmaxf(v.x - cut, 0.0f);
        o.y = fmaxf(v.y - cut, 0.0f);
        o.z = fmaxf(v.z - cut, 0.0f);
        o.w = fmaxf(v.w - cut, 0.0f);
        outv[i] = o;
    }
}

extern "C" void kernel_launch(void* const* d_in, const int* in_sizes, int n_in,
                              void* d_out, int out_size, void* d_ws, size_t ws_size,
                              hipStream_t stream) {
    const float* in = (const float*)d_in[0];
    float* out = (float*)d_out;
    const int N = 65536;                       // row length (fixed by reference)
    const int B = in_sizes[0] / N;             // 1024 rows
    const int k = (int)(((long long)N * 4) / 5);  // int(N*0.8) = 52428
    xsrelu_perc_kernel<<<dim3(B), dim3(TPB), 0, stream>>>(in, out, N, k);
}

// Round 3
// 500.786 us; speedup vs baseline: 1.0674x; 1.0674x over previous
//
#include <hip/hip_runtime.h>

// XSReLU percentile, split into two well-shaped kernels:
//  K1 (cutoff_kernel): per-row exact 80th-percentile via single-read band
//     gather [0.72, 0.98) + fine histogram select; exact 3-pass fallback.
//  K2 (relu_kernel):    pure streaming relu(x - cut[row]).
// Cutoffs live in d_ws (rewritten every call; harness poisons ws).

#define TPB1  1024
#define NB    4096    // fine bins over [LO,HI) (fast path) / top-12 ord bits (fallback)
#define CAP   8192    // candidate buffer (expected ~4.7k for N(0,1))
#define TINY  64      // per-bin candidates (expected ~3)
#define BLO   0.72f
#define BHI   0.98f

#define TPB2  256
#define VPT   16      // float4 per thread in relu kernel

__device__ __forceinline__ unsigned f2ord(float f) {
    unsigned u = __float_as_uint(f);
    return (u & 0x80000000u) ? ~u : (u | 0x80000000u);
}
__device__ __forceinline__ float ord2f(unsigned u) {
    unsigned b = (u & 0x80000000u) ? (u ^ 0x80000000u) : ~u;
    return __uint_as_float(b);
}

__global__ __launch_bounds__(TPB1)
void cutoff_kernel(const float* __restrict__ in, float* __restrict__ cut,
                   int N, int k) {
    const int row  = blockIdx.x;
    const int tid  = threadIdx.x;
    const int lane = tid & 63;
    const int nv   = N >> 2;
    const float SCALE = (float)NB / (BHI - BLO);
    const float4* __restrict__ rowv = (const float4*)(in + (size_t)row * (size_t)N);

    __shared__ unsigned hist[NB];
    __shared__ unsigned cand[CAP];
    __shared__ unsigned part[TPB1];
    __shared__ unsigned tiny[TINY];
    __shared__ unsigned s_cnt, s_below, s_cum, s_tc;
    __shared__ int s_bin, s_fb;
    __shared__ float s_cut;

    for (int i = tid; i < NB; i += TPB1) hist[i] = 0u;
    if (tid == 0) { s_cnt = 0u; s_below = 0u; s_tc = 0u; s_fb = 0; }
    __syncthreads();

    // ---- single streaming read: count below-band, gather band candidates ----
    unsigned below = 0;
    for (int i = tid; i < nv; i += TPB1) {
        float4 v = rowv[i];
        float vals[4] = {v.x, v.y, v.z, v.w};
        #pragma unroll
        for (int j = 0; j < 4; ++j) {
            float f = vals[j];
            below += (f < BLO) ? 1u : 0u;
            bool pred = (f >= BLO) && (f < BHI);
            unsigned long long m = __ballot(pred);
            if (m) {
                int leader = __ffsll((long long)m) - 1;
                unsigned base = 0;
                if (lane == leader) base = atomicAdd(&s_cnt, (unsigned)__popcll(m));
                base = __shfl(base, leader);
                if (pred) {
                    unsigned p = base + (unsigned)__popcll(m & ((1ull << lane) - 1ull));
                    if (p < CAP) cand[p] = __float_as_uint(f) | 0x80000000u; // positive ord
                    int b = (int)((f - BLO) * SCALE);
                    b = b < 0 ? 0 : (b >= NB ? NB - 1 : b);
                    atomicAdd(&hist[b], 1u);
                }
            }
        }
    }
    #pragma unroll
    for (int o = 32; o > 0; o >>= 1) below += __shfl_down(below, o);
    if (lane == 0) atomicAdd(&s_below, below);
    __syncthreads();

    const unsigned M0 = s_cnt;
    const long long r2ll = (long long)k - (long long)s_below;

    if (M0 > CAP || r2ll < 0 || r2ll >= (long long)M0) {
        if (tid == 0) s_fb = 1;          // bracket miss -> exact fallback
    } else {
        const unsigned r2 = (unsigned)r2ll;
        // block scan of hist (4 bins/thread)
        const int base4 = tid * 4;
        unsigned s = hist[base4] + hist[base4 + 1] + hist[base4 + 2] + hist[base4 + 3];
        part[tid] = s;
        __syncthreads();
        for (int off = 1; off < TPB1; off <<= 1) {
            unsigned add = (tid >= off) ? part[tid - off] : 0u;
            __syncthreads();
            part[tid] += add;
            __syncthreads();
        }
        unsigned incl = part[tid], excl = incl - s;
        if (r2 >= excl && r2 < incl) {
            unsigned c = excl;
            #pragma unroll
            for (int j = 0; j < 4; ++j) {
                unsigned h = hist[base4 + j];
                if (r2 < c + h) { s_bin = base4 + j; s_cum = c; break; }
                c += h;
            }
        }
        __syncthreads();
        const int bin = s_bin;
        const unsigned r3 = r2 - s_cum;
        if (tid < 64) {
            // gather this bin's candidates into tiny[]
            for (unsigned i = (unsigned)lane; i < M0; i += 64u) {
                unsigned u = cand[i];
                float f = __uint_as_float(u ^ 0x80000000u);
                int b = (int)((f - BLO) * SCALE);
                b = b < 0 ? 0 : (b >= NB ? NB - 1 : b);
                bool pred = (b == bin);
                unsigned long long mm = __ballot(pred);
                if (mm) {
                    int leader = __ffsll((long long)mm) - 1;
                    unsigned tb = 0;
                    if (lane == leader) tb = atomicAdd(&s_tc, (unsigned)__popcll(mm));
                    tb = __shfl(tb, leader);
                    if (pred) {
                        unsigned p = tb + (unsigned)__popcll(mm & ((1ull << lane) - 1ull));
                        if (p < TINY) tiny[p] = u;
                    }
                }
            }
            unsigned c = s_tc;
            if (c > TINY) { if (lane == 0) s_fb = 1; }
            else {
                unsigned uj = (lane < (int)c) ? tiny[lane] : 0xFFFFFFFFu;
                unsigned less = 0, eq = 0;
                for (unsigned i2 = 0; i2 < c; ++i2) {
                    unsigned ui = tiny[i2];
                    less += (ui < uj) ? 1u : 0u;
                    eq   += (ui == uj) ? 1u : 0u;
                }
                bool cond = (lane < (int)c) && (less <= r3) && (r3 < less + eq);
                unsigned long long cm = __ballot(cond);
                if (cond && lane == __ffsll((long long)cm) - 1)
                    s_cut = __uint_as_float(uj ^ 0x80000000u);
            }
        }
    }
    __syncthreads();

    if (s_fb) {
        // ---- exact fallback: 12-bit ord histogram + gather + radix select ----
        for (int i = tid; i < NB; i += TPB1) hist[i] = 0u;
        if (tid == 0) s_cnt = 0u;
        __syncthreads();
        for (int i = tid; i < nv; i += TPB1) {
            float4 v = rowv[i];
            float vals[4] = {v.x, v.y, v.z, v.w};
            #pragma unroll
            for (int j = 0; j < 4; ++j) atomicAdd(&hist[f2ord(vals[j]) >> 20], 1u);
        }
        __syncthreads();
        const int base4 = tid * 4;
        unsigned s = hist[base4] + hist[base4 + 1] + hist[base4 + 2] + hist[base4 + 3];
        part[tid] = s;
        __syncthreads();
        for (int off = 1; off < TPB1; off <<= 1) {
            unsigned add = (tid >= off) ? part[tid - off] : 0u;
            __syncthreads();
            part[tid] += add;
            __syncthreads();
        }
        const unsigned rk = (unsigned)k;
        unsigned incl = part[tid], excl = incl - s;
        if (rk >= excl && rk < incl) {
            unsigned c = excl;
            #pragma unroll
            for (int j = 0; j < 4; ++j) {
                unsigned h = hist[base4 + j];
                if (rk < c + h) { s_bin = base4 + j; s_cum = c; break; }
                c += h;
            }
        }
        __syncthreads();
        const unsigned bin = (unsigned)s_bin;
        for (int i = tid; i < nv; i += TPB1) {
            float4 v = rowv[i];
            float vals[4] = {v.x, v.y, v.z, v.w};
            #pragma unroll
            for (int j = 0; j < 4; ++j) {
                unsigned u = f2ord(vals[j]);
                bool pred = ((u >> 20) == bin);
                unsigned long long m = __ballot(pred);
                if (m) {
                    int leader = __ffsll((long long)m) - 1;
                    unsigned b2 = 0;
                    if (lane == leader) b2 = atomicAdd(&s_cnt, (unsigned)__popcll(m));
                    b2 = __shfl(b2, leader);
                    if (pred) {
                        unsigned p = b2 + (unsigned)__popcll(m & ((1ull << lane) - 1ull));
                        if (p < CAP) cand[p] = u;
                    }
                }
            }
        }
        __syncthreads();
        if (tid < 64) {
            unsigned M2 = s_cnt; if (M2 > CAP) M2 = CAP;
            unsigned prefix = bin;
            unsigned rr = (unsigned)k - s_cum;
            for (int bit = 19; bit >= 0; --bit) {
                unsigned want0 = prefix << 1;
                unsigned cnt = 0;
                for (unsigned i = (unsigned)lane; i < M2; i += 64u)
                    if ((cand[i] >> bit) == want0) cnt++;
                #pragma unroll
                for (int o = 32; o > 0; o >>= 1) cnt += __shfl_down(cnt, o);
                cnt = __shfl(cnt, 0);
                if (rr < cnt) prefix = want0;
                else { rr -= cnt; prefix = want0 | 1u; }
            }
            if (lane == 0) s_cut = ord2f(prefix);
        }
        __syncthreads();
    }

    if (tid == 0) cut[row] = s_cut;
}

__global__ __launch_bounds__(TPB2)
void relu_kernel(const float* __restrict__ in, const float* __restrict__ cut,
                 float* __restrict__ out, int N) {
    const int f4PerBlock = TPB2 * VPT;                 // 4096 float4
    const int bpr = (N >> 2) / f4PerBlock;             // blocks per row (4)
    const int row = blockIdx.x / bpr;
    const float c = cut[row];
    const size_t base = (size_t)blockIdx.x * (size_t)f4PerBlock + threadIdx.x;
    const float4* __restrict__ iv = (const float4*)in;
    float4* __restrict__ ov = (float4*)out;
    #pragma unroll
    for (int j = 0; j < VPT; ++j) {
        size_t idx = base + (size_t)j * TPB2;
        float4 v = iv[idx];
        float4 o;
        o.x = fmaxf(v.x - c, 0.0f);
        o.y = fmaxf(v.y - c, 0.0f);
        o.z = fmaxf(v.z - c, 0.0f);
        o.w = fmaxf(v.w - c, 0.0f);
        ov[idx] = o;
    }
}

extern "C" void kernel_launch(void* const* d_in, const int* in_sizes, int n_in,
                              void* d_out, int out_size, void* d_ws, size_t ws_size,
                              hipStream_t stream) {
    const float* in = (const float*)d_in[0];
    float* out = (float*)d_out;
    float* cut = (float*)d_ws;
    const int N = 65536;
    const int B = in_sizes[0] / N;                        // 1024
    const int k = (int)(((long long)N * 4) / 5);          // 52428

    cutoff_kernel<<<dim3(B), dim3(TPB1), 0, stream>>>(in, cut, N, k);

    const int totalF4 = (B * N) >> 2;
    const int blocks2 = totalF4 / (TPB2 * VPT);           // 4096
    relu_kernel<<<dim3(blocks2), dim3(TPB2), 0, stream>>>(in, cut, out, N);
}

// Round 4
// 488.909 us; speedup vs baseline: 1.0934x; 1.0243x over previous
//
#include <hip/hip_runtime.h>

// XSReLU percentile (B=1024 rows, N=65536 fp32), exact 80th percentile.
//  K1 cutoff_kernel: one streaming read/row; direct-atomic gather of the
//     [0.72,0.98) band (~4.7k cands) into LDS; fine histogram built FROM LDS;
//     hierarchical wave-scan bin find; tiny exact select.
//     Fallback: 3-pass exact histogram refinement (no capacity assumptions).
//  K2 relu_kernel: pure stream relu(x - cut[row]).

#define TPB1  512
#define NB    2048    // fine bins (fast path) / radix bins (fallback)
#define CAP   6144    // candidate buffer; expected 4738 +- 66 (1 sigma)
#define TINY  64
#define BLO   0.72f
#define BHI   0.98f

#define TPB2  256
#define VPT   16

__device__ __forceinline__ unsigned f2ord(float f) {
    unsigned u = __float_as_uint(f);
    return (u & 0x80000000u) ? ~u : (u | 0x80000000u);
}
__device__ __forceinline__ float ord2f(unsigned u) {
    unsigned b = (u & 0x80000000u) ? (u ^ 0x80000000u) : ~u;
    return __uint_as_float(b);
}

// All TPB1 threads participate. Finds bin b* s.t. cum(hist[0..b*)) <= r < cum+hist[b*].
// Writes *s_bin and *s_cum (cumulative before bin). hist has NB bins, 4/thread.
__device__ __forceinline__ void hist_select(const unsigned* hist, unsigned r, int tid,
                                            unsigned* wsum, unsigned* wbase,
                                            int* s_bin, unsigned* s_cum) {
    const int lane = tid & 63, wid = tid >> 6;
    const int b0 = tid * (NB / TPB1);                       // 4 bins per thread
    unsigned h0 = hist[b0], h1 = hist[b0+1], h2 = hist[b0+2], h3 = hist[b0+3];
    unsigned s = h0 + h1 + h2 + h3;
    unsigned incl = s;                                      // wave inclusive scan
    #pragma unroll
    for (int off = 1; off < 64; off <<= 1) {
        unsigned t = __shfl_up(incl, off);
        if (lane >= off) incl += t;
    }
    if (lane == 63) wsum[wid] = incl;                       // wave totals
    __syncthreads();
    if (tid == 0) {
        unsigned c = 0;
        #pragma unroll
        for (int w = 0; w < TPB1/64; ++w) { wbase[w] = c; c += wsum[w]; }
    }
    __syncthreads();
    unsigned excl = wbase[wid] + incl - s;                  // global excl prefix of this thread
    if (r >= excl && r < excl + s) {                        // exactly one thread
        unsigned c = excl;
        if (r < c + h0)        { *s_bin = b0;     *s_cum = c; }
        else { c += h0; if (r < c + h1) { *s_bin = b0 + 1; *s_cum = c; }
        else { c += h1; if (r < c + h2) { *s_bin = b0 + 2; *s_cum = c; }
        else { c += h2;                   *s_bin = b0 + 3; *s_cum = c; } } }
    }
    __syncthreads();
}

__global__ __launch_bounds__(TPB1, 8)
void cutoff_kernel(const float* __restrict__ in, float* __restrict__ cut,
                   int N, int k) {
    const int row  = blockIdx.x;
    const int tid  = threadIdx.x;
    const int lane = tid & 63;
    const int nv   = N >> 2;
    const float SCALE = (float)NB / (BHI - BLO);
    const float4* __restrict__ rowv = (const float4*)(in + (size_t)row * (size_t)N);

    __shared__ unsigned hist[NB];
    __shared__ unsigned cand[CAP];
    __shared__ unsigned tiny[TINY];
    __shared__ unsigned wsum[TPB1/64], wbase[TPB1/64];
    __shared__ unsigned s_cnt, s_below, s_cum, s_tc;
    __shared__ int s_bin, s_fb;
    __shared__ float s_cut;

    for (int i = tid; i < NB; i += TPB1) hist[i] = 0u;
    if (tid == 0) { s_cnt = 0u; s_below = 0u; s_tc = 0u; s_fb = 0; }
    __syncthreads();

    // ---- Pass A: single streaming read. 3 compares/elem; rare direct atomics ----
    unsigned below = 0;
    for (int i = tid; i < nv; i += TPB1) {
        float4 v = rowv[i];
        float vals[4] = {v.x, v.y, v.z, v.w};
        #pragma unroll
        for (int j = 0; j < 4; ++j) {
            float f = vals[j];
            below += (f < BLO) ? 1u : 0u;
            if (f >= BLO && f < BHI) {                       // ~7% of lanes
                unsigned p = atomicAdd(&s_cnt, 1u);
                if (p < CAP) cand[p] = __float_as_uint(f);   // positive: raw bits monotone
            }
        }
    }
    #pragma unroll
    for (int o = 32; o > 0; o >>= 1) below += __shfl_down(below, o);
    if (lane == 0) atomicAdd(&s_below, below);
    __syncthreads();

    const unsigned M0 = s_cnt;
    const long long r2ll = (long long)k - (long long)s_below;
    const bool fast = (M0 <= CAP) && (r2ll >= 0) && (r2ll < (long long)M0);

    if (fast) {
        const unsigned r2 = (unsigned)r2ll;
        // fine histogram built from LDS candidates (~9 elems/thread)
        for (unsigned i = tid; i < M0; i += TPB1) {
            float f = __uint_as_float(cand[i]);
            int b = (int)((f - BLO) * SCALE);
            b = b < 0 ? 0 : (b >= NB ? NB - 1 : b);
            atomicAdd(&hist[b], 1u);
        }
        __syncthreads();
        hist_select(hist, r2, tid, wsum, wbase, &s_bin, &s_cum);
        const int bin = s_bin;
        const unsigned r3 = r2 - s_cum;
        for (unsigned i = tid; i < M0; i += TPB1) {
            unsigned u = cand[i];
            float f = __uint_as_float(u);
            int b = (int)((f - BLO) * SCALE);
            b = b < 0 ? 0 : (b >= NB ? NB - 1 : b);
            if (b == bin) { unsigned p = atomicAdd(&s_tc, 1u); if (p < TINY) tiny[p] = u; }
        }
        __syncthreads();
        const unsigned c = s_tc;
        if (c > TINY) { if (tid == 0) s_fb = 1; }            // absurdly unlikely
        else if (tid < 64) {
            unsigned uj = (lane < (int)c) ? tiny[lane] : 0xFFFFFFFFu;
            unsigned less = 0, eq = 0;
            for (unsigned i2 = 0; i2 < c; ++i2) {
                unsigned ui = tiny[i2];
                less += (ui < uj) ? 1u : 0u;
                eq   += (ui == uj) ? 1u : 0u;
            }
            bool cond = (lane < (int)c) && (less <= r3) && (r3 < less + eq);
            unsigned long long cm = __ballot(cond);
            if (cond && lane == __ffsll((long long)cm) - 1)
                s_cut = __uint_as_float(uj);
        }
    } else {
        if (tid == 0) s_fb = 1;
    }
    __syncthreads();

    if (s_fb) {
        // ---- exact fallback: 3-pass ord-bit histogram refinement (11/11/10) ----
        unsigned prefix = 0;
        unsigned rr = (unsigned)k;
        const int shifts[3] = {21, 10, 0};
        const int bitsc[3]  = {11, 11, 10};
        for (int pass = 0; pass < 3; ++pass) {
            const int sh = shifts[pass];
            const unsigned nb = 1u << bitsc[pass];
            for (int i = tid; i < NB; i += TPB1) hist[i] = 0u;
            __syncthreads();
            for (int i = tid; i < nv; i += TPB1) {
                float4 v = rowv[i];
                float vals[4] = {v.x, v.y, v.z, v.w};
                #pragma unroll
                for (int j = 0; j < 4; ++j) {
                    unsigned u = f2ord(vals[j]);
                    if (pass == 0 || (u >> (sh + bitsc[pass])) == prefix)
                        atomicAdd(&hist[(u >> sh) & (nb - 1u)], 1u);
                }
            }
            __syncthreads();
            hist_select(hist, rr, tid, wsum, wbase, &s_bin, &s_cum);
            prefix = (prefix << bitsc[pass]) | (unsigned)s_bin;
            rr -= s_cum;
            __syncthreads();
        }
        if (tid == 0) s_cut = ord2f(prefix);
        __syncthreads();
    }

    if (tid == 0) cut[row] = s_cut;
}

__global__ __launch_bounds__(TPB2)
void relu_kernel(const float* __restrict__ in, const float* __restrict__ cut,
                 float* __restrict__ out, int N) {
    const int f4PerBlock = TPB2 * VPT;                 // 4096 float4
    const int bpr = (N >> 2) / f4PerBlock;             // 4 blocks per row
    const int row = blockIdx.x / bpr;
    const float c = cut[row];
    const size_t base = (size_t)blockIdx.x * (size_t)f4PerBlock + threadIdx.x;
    const float4* __restrict__ iv = (const float4*)in;
    float4* __restrict__ ov = (float4*)out;
    #pragma unroll
    for (int j = 0; j < VPT; ++j) {
        size_t idx = base + (size_t)j * TPB2;
        float4 v = iv[idx];
        float4 o;
        o.x = fmaxf(v.x - c, 0.0f);
        o.y = fmaxf(v.y - c, 0.0f);
        o.z = fmaxf(v.z - c, 0.0f);
        o.w = fmaxf(v.w - c, 0.0f);
        ov[idx] = o;
    }
}

extern "C" void kernel_launch(void* const* d_in, const int* in_sizes, int n_in,
                              void* d_out, int out_size, void* d_ws, size_t ws_size,
                              hipStream_t stream) {
    const float* in = (const float*)d_in[0];
    float* out = (float*)d_out;
    float* cut = (float*)d_ws;
    const int N = 65536;
    const int B = in_sizes[0] / N;                        // 1024
    const int k = (int)(((long long)N * 4) / 5);          // 52428

    cutoff_kernel<<<dim3(B), dim3(TPB1), 0, stream>>>(in, cut, N, k);

    const int totalF4 = (B * N) >> 2;
    const int blocks2 = totalF4 / (TPB2 * VPT);           // 4096
    relu_kernel<<<dim3(blocks2), dim3(TPB2), 0, stream>>>(in, cut, out, N);
}

// Round 5
// 475.015 us; speedup vs baseline: 1.1254x; 1.0292x over previous
//
#include <hip/hip_runtime.h>

// XSReLU percentile (B=1024 rows, N=65536 fp32), exact 80th percentile.
// Single fused kernel, one 512-thread block per row, ROW HELD IN REGISTERS
// (32 float4/thread): one HBM read + one HBM write total.
//   pass A: load row -> regs; count below-band; gather [0.72,0.98) band
//           (~4.7k cands for N(0,1)) into LDS via direct atomics.
//   select: fine 2048-bin histogram of cands + hierarchical wave scan +
//           tiny exact select (bit-identical to sort()[k]).
//   fallback (bracket miss; never taken for N(0,1)): exact 3-pass radix
//           histogram refinement OVER REGISTERS - no extra HBM traffic.
//   pass C: write relu(v - cut) from registers.

#define TPB   512
#define F4PT  32      // float4 per thread: 512*32*4 = 65536 elements
#define NB    2048    // fine bins (fast) / max radix bins (fallback)
#define CAP   6144    // band candidate buffer; expected 4738 +- 66 (1 sigma)
#define TINY  64
#define BLO   0.72f
#define BHI   0.98f

__device__ __forceinline__ unsigned f2ord(float f) {
    unsigned u = __float_as_uint(f);
    return (u & 0x80000000u) ? ~u : (u | 0x80000000u);
}
__device__ __forceinline__ float ord2f(unsigned u) {
    unsigned b = (u & 0x80000000u) ? (u ^ 0x80000000u) : ~u;
    return __uint_as_float(b);
}

// All TPB threads participate. Finds bin b* with cum(hist[0..b*)) <= r < cum+hist[b*].
__device__ __forceinline__ void hist_select(const unsigned* hist, unsigned r, int tid,
                                            unsigned* wsum, unsigned* wbase,
                                            int* s_bin, unsigned* s_cum) {
    const int lane = tid & 63, wid = tid >> 6;
    const int b0 = tid * (NB / TPB);                        // 4 bins per thread
    unsigned h0 = hist[b0], h1 = hist[b0+1], h2 = hist[b0+2], h3 = hist[b0+3];
    unsigned s = h0 + h1 + h2 + h3;
    unsigned incl = s;                                      // wave inclusive scan
    #pragma unroll
    for (int off = 1; off < 64; off <<= 1) {
        unsigned t = __shfl_up(incl, off);
        if (lane >= off) incl += t;
    }
    if (lane == 63) wsum[wid] = incl;
    __syncthreads();
    if (tid == 0) {
        unsigned c = 0;
        #pragma unroll
        for (int w = 0; w < TPB/64; ++w) { wbase[w] = c; c += wsum[w]; }
    }
    __syncthreads();
    unsigned excl = wbase[wid] + incl - s;                  // global exclusive prefix
    if (r >= excl && r < excl + s) {                        // exactly one thread
        unsigned c = excl;
        if (r < c + h0)        { *s_bin = b0;     *s_cum = c; }
        else { c += h0; if (r < c + h1) { *s_bin = b0 + 1; *s_cum = c; }
        else { c += h1; if (r < c + h2) { *s_bin = b0 + 2; *s_cum = c; }
        else { c += h2;                   *s_bin = b0 + 3; *s_cum = c; } } }
    }
    __syncthreads();
}

__global__ __launch_bounds__(TPB)
void xsrelu_fused(const float* __restrict__ in, float* __restrict__ out,
                  int N, int k) {
    const int row  = blockIdx.x;
    const int tid  = threadIdx.x;
    const int lane = tid & 63;
    const float SCALE = (float)NB / (BHI - BLO);
    const float4* __restrict__ rowv = (const float4*)(in + (size_t)row * (size_t)N);
    float4* __restrict__ outv = (float4*)(out + (size_t)row * (size_t)N);

    __shared__ unsigned hist[NB];
    __shared__ unsigned cand[CAP];
    __shared__ unsigned tiny[TINY];
    __shared__ unsigned wsum[TPB/64], wbase[TPB/64];
    __shared__ unsigned s_cnt, s_below, s_cum, s_tc;
    __shared__ int s_bin, s_fb;
    __shared__ float s_cut;

    for (int i = tid; i < NB; i += TPB) hist[i] = 0u;
    if (tid == 0) { s_cnt = 0u; s_below = 0u; s_tc = 0u; s_fb = 0; }
    __syncthreads();

    // ---- load entire row into registers (coalesced, 32 indep dwordx4/thread) ----
    float4 v[F4PT];
    #pragma unroll
    for (int j = 0; j < F4PT; ++j) v[j] = rowv[tid + j * TPB];

    // ---- pass A over registers: below count + band gather ----
    unsigned below = 0;
    #pragma unroll
    for (int j = 0; j < F4PT; ++j) {
        const float f0 = v[j].x, f1 = v[j].y, f2 = v[j].z, f3 = v[j].w;
        below += (f0 < BLO) ? 1u : 0u;
        below += (f1 < BLO) ? 1u : 0u;
        below += (f2 < BLO) ? 1u : 0u;
        below += (f3 < BLO) ? 1u : 0u;
        if (f0 >= BLO && f0 < BHI) { unsigned p = atomicAdd(&s_cnt, 1u); if (p < CAP) cand[p] = __float_as_uint(f0); }
        if (f1 >= BLO && f1 < BHI) { unsigned p = atomicAdd(&s_cnt, 1u); if (p < CAP) cand[p] = __float_as_uint(f1); }
        if (f2 >= BLO && f2 < BHI) { unsigned p = atomicAdd(&s_cnt, 1u); if (p < CAP) cand[p] = __float_as_uint(f2); }
        if (f3 >= BLO && f3 < BHI) { unsigned p = atomicAdd(&s_cnt, 1u); if (p < CAP) cand[p] = __float_as_uint(f3); }
    }
    #pragma unroll
    for (int o = 32; o > 0; o >>= 1) below += __shfl_down(below, o);
    if (lane == 0) atomicAdd(&s_below, below);
    __syncthreads();

    const unsigned M0 = s_cnt;
    const long long r2ll = (long long)k - (long long)s_below;
    const bool fast = (M0 <= CAP) && (r2ll >= 0) && (r2ll < (long long)M0);

    if (fast) {
        const unsigned r2 = (unsigned)r2ll;
        // fine histogram from LDS candidates (~9 elems/thread, low contention)
        for (unsigned i = tid; i < M0; i += TPB) {
            float f = __uint_as_float(cand[i]);
            int b = (int)((f - BLO) * SCALE);
            b = b < 0 ? 0 : (b >= NB ? NB - 1 : b);
            atomicAdd(&hist[b], 1u);
        }
        __syncthreads();
        hist_select(hist, r2, tid, wsum, wbase, &s_bin, &s_cum);
        const int bin = s_bin;
        const unsigned r3 = r2 - s_cum;
        for (unsigned i = tid; i < M0; i += TPB) {
            unsigned u = cand[i];
            float f = __uint_as_float(u);
            int b = (int)((f - BLO) * SCALE);
            b = b < 0 ? 0 : (b >= NB ? NB - 1 : b);
            if (b == bin) { unsigned p = atomicAdd(&s_tc, 1u); if (p < TINY) tiny[p] = u; }
        }
        __syncthreads();
        const unsigned c = s_tc;
        if (c > TINY) { if (tid == 0) s_fb = 1; }
        else if (tid < 64) {
            unsigned uj = (lane < (int)c) ? tiny[lane] : 0xFFFFFFFFu;
            unsigned less = 0, eq = 0;
            for (unsigned i2 = 0; i2 < c; ++i2) {
                unsigned ui = tiny[i2];
                less += (ui < uj) ? 1u : 0u;
                eq   += (ui == uj) ? 1u : 0u;
            }
            bool cond = (lane < (int)c) && (less <= r3) && (r3 < less + eq);
            unsigned long long cm = __ballot(cond);
            if (cond && lane == __ffsll((long long)cm) - 1)
                s_cut = __uint_as_float(uj);    // positive floats: raw bits monotone
        }
    } else {
        if (tid == 0) s_fb = 1;
    }
    __syncthreads();

    if (s_fb) {
        // ---- exact fallback over REGISTERS: 3-pass radix refinement (11/11/10) ----
        unsigned prefix = 0;
        unsigned rr = (unsigned)k;
        const int shifts[3] = {21, 10, 0};
        const int bitsc[3]  = {11, 11, 10};
        for (int pass = 0; pass < 3; ++pass) {
            const int sh = shifts[pass];
            const unsigned nbm = (1u << bitsc[pass]) - 1u;
            for (int i = tid; i < NB; i += TPB) hist[i] = 0u;
            __syncthreads();
            #pragma unroll
            for (int j = 0; j < F4PT; ++j) {
                const float vals[4] = {v[j].x, v[j].y, v[j].z, v[j].w};
                #pragma unroll
                for (int q = 0; q < 4; ++q) {
                    unsigned u = f2ord(vals[q]);
                    if (pass == 0 || (u >> (sh + bitsc[pass])) == prefix)
                        atomicAdd(&hist[(u >> sh) & nbm], 1u);
                }
            }
            __syncthreads();
            hist_select(hist, rr, tid, wsum, wbase, &s_bin, &s_cum);
            prefix = (prefix << bitsc[pass]) | (unsigned)s_bin;
            rr -= s_cum;
        }
        if (tid == 0) s_cut = ord2f(prefix);
        __syncthreads();
    }

    const float cut = s_cut;

    // ---- pass C: write relu(v - cut) straight from registers ----
    #pragma unroll
    for (int j = 0; j < F4PT; ++j) {
        float4 o;
        o.x = fmaxf(v[j].x - cut, 0.0f);
        o.y = fmaxf(v[j].y - cut, 0.0f);
        o.z = fmaxf(v[j].z - cut, 0.0f);
        o.w = fmaxf(v[j].w - cut, 0.0f);
        outv[tid + j * TPB] = o;
    }
}

extern "C" void kernel_launch(void* const* d_in, const int* in_sizes, int n_in,
                              void* d_out, int out_size, void* d_ws, size_t ws_size,
                              hipStream_t stream) {
    const float* in = (const float*)d_in[0];
    float* out = (float*)d_out;
    const int N = 65536;
    const int B = in_sizes[0] / N;                        // 1024
    const int k = (int)(((long long)N * 4) / 5);          // 52428

    xsrelu_fused<<<dim3(B), dim3(TPB), 0, stream>>>(in, out, N, k);
}

// Round 6
// 457.092 us; speedup vs baseline: 1.1695x; 1.0392x over previous
//
#include <hip/hip_runtime.h>

// XSReLU percentile (B=1024 rows, N=65536 fp32), exact 80th percentile.
// Single fused kernel, one 512-thread block per row, row held in registers
// (32 float4/thread): one HBM read + one HBM write total.
//   pass A: load row -> regs; count below-band & band cands (pure VALU);
//           block exclusive scan -> private LDS ranges; scatter cands
//           (ZERO same-address atomic contention).
//   select: fine 2048-bin histogram of cands + hierarchical wave scan +
//           tiny exact select (bit-identical to sort()[k]).
//   fallback (bracket miss; never taken for N(0,1)): exact 3-pass radix
//           histogram refinement over registers - no extra HBM traffic.
//   pass C: write relu(v - cut) from registers.

#define TPB   512
#define F4PT  32      // float4 per thread: 512*32*4 = 65536 elements
#define NB    2048    // fine bins (fast) / max radix bins (fallback)
#define CAP   6144    // band candidate buffer; expected 4738 +- 66 (1 sigma)
#define TINY  64
#define BLO   0.72f
#define BHI   0.98f
#define NWAVE (TPB/64)

__device__ __forceinline__ unsigned f2ord(float f) {
    unsigned u = __float_as_uint(f);
    return (u & 0x80000000u) ? ~u : (u | 0x80000000u);
}
__device__ __forceinline__ float ord2f(unsigned u) {
    unsigned b = (u & 0x80000000u) ? (u ^ 0x80000000u) : ~u;
    return __uint_as_float(b);
}
__device__ __forceinline__ bool in_band(float f) { return f >= BLO && f < BHI; }

// All TPB threads participate. Finds bin b* with cum(hist[0..b*)) <= r < cum+hist[b*].
__device__ __forceinline__ void hist_select(const unsigned* hist, unsigned r, int tid,
                                            unsigned* wsum, unsigned* wbase,
                                            int* s_bin, unsigned* s_cum) {
    const int lane = tid & 63, wid = tid >> 6;
    const int b0 = tid * (NB / TPB);                        // 4 bins per thread
    unsigned h0 = hist[b0], h1 = hist[b0+1], h2 = hist[b0+2], h3 = hist[b0+3];
    unsigned s = h0 + h1 + h2 + h3;
    unsigned incl = s;                                      // wave inclusive scan
    #pragma unroll
    for (int off = 1; off < 64; off <<= 1) {
        unsigned t = __shfl_up(incl, off);
        if (lane >= off) incl += t;
    }
    if (lane == 63) wsum[wid] = incl;
    __syncthreads();
    if (tid == 0) {
        unsigned c = 0;
        #pragma unroll
        for (int w = 0; w < NWAVE; ++w) { wbase[w] = c; c += wsum[w]; }
    }
    __syncthreads();
    unsigned excl = wbase[wid] + incl - s;                  // global exclusive prefix
    if (r >= excl && r < excl + s) {                        // exactly one thread
        unsigned c = excl;
        if (r < c + h0)        { *s_bin = b0;     *s_cum = c; }
        else { c += h0; if (r < c + h1) { *s_bin = b0 + 1; *s_cum = c; }
        else { c += h1; if (r < c + h2) { *s_bin = b0 + 2; *s_cum = c; }
        else { c += h2;                   *s_bin = b0 + 3; *s_cum = c; } } }
    }
    __syncthreads();
}

__global__ __launch_bounds__(TPB)
void xsrelu_fused(const float* __restrict__ in, float* __restrict__ out,
                  int N, int k) {
    const int row  = blockIdx.x;
    const int tid  = threadIdx.x;
    const int lane = tid & 63;
    const int wid  = tid >> 6;
    const float SCALE = (float)NB / (BHI - BLO);
    const float4* __restrict__ rowv = (const float4*)(in + (size_t)row * (size_t)N);
    float4* __restrict__ outv = (float4*)(out + (size_t)row * (size_t)N);

    __shared__ unsigned hist[NB];
    __shared__ unsigned cand[CAP];
    __shared__ unsigned tiny[TINY];
    __shared__ unsigned wsum[NWAVE], wbase[NWAVE];
    __shared__ unsigned s_cnt, s_below, s_cum, s_tc;
    __shared__ int s_bin, s_fb;
    __shared__ float s_cut;

    for (int i = tid; i < NB; i += TPB) hist[i] = 0u;
    if (tid == 0) { s_below = 0u; s_tc = 0u; s_fb = 0; }
    __syncthreads();

    // ---- load entire row into registers (coalesced, 32 indep dwordx4/thread) ----
    float4 v[F4PT];
    #pragma unroll
    for (int j = 0; j < F4PT; ++j) v[j] = rowv[tid + j * TPB];

    // ---- pass A.1: pure-VALU counts over registers ----
    unsigned below = 0, cnt = 0;
    #pragma unroll
    for (int j = 0; j < F4PT; ++j) {
        const float f0 = v[j].x, f1 = v[j].y, f2 = v[j].z, f3 = v[j].w;
        below += (f0 < BLO) ? 1u : 0u;
        below += (f1 < BLO) ? 1u : 0u;
        below += (f2 < BLO) ? 1u : 0u;
        below += (f3 < BLO) ? 1u : 0u;
        cnt += in_band(f0) ? 1u : 0u;
        cnt += in_band(f1) ? 1u : 0u;
        cnt += in_band(f2) ? 1u : 0u;
        cnt += in_band(f3) ? 1u : 0u;
    }
    // below total: wave reduce + 1 atomic per wave
    unsigned bsum = below;
    #pragma unroll
    for (int o = 32; o > 0; o >>= 1) bsum += __shfl_down(bsum, o);
    if (lane == 0) atomicAdd(&s_below, bsum);

    // ---- pass A.2: block exclusive scan of cnt -> private cand ranges ----
    unsigned incl = cnt;
    #pragma unroll
    for (int off = 1; off < 64; off <<= 1) {
        unsigned t = __shfl_up(incl, off);
        if (lane >= off) incl += t;
    }
    if (lane == 63) wsum[wid] = incl;
    __syncthreads();
    if (tid == 0) {
        unsigned c = 0;
        #pragma unroll
        for (int w = 0; w < NWAVE; ++w) { wbase[w] = c; c += wsum[w]; }
        s_cnt = c;                                   // total band candidates
    }
    __syncthreads();
    unsigned p = wbase[wid] + incl - cnt;            // this thread's write cursor

    // ---- pass A.3: scatter candidates (no contention) ----
    #pragma unroll
    for (int j = 0; j < F4PT; ++j) {
        const float vals[4] = {v[j].x, v[j].y, v[j].z, v[j].w};
        #pragma unroll
        for (int q = 0; q < 4; ++q) {
            if (in_band(vals[q])) { if (p < CAP) cand[p] = __float_as_uint(vals[q]); ++p; }
        }
    }
    __syncthreads();

    const unsigned M0 = s_cnt;
    const long long r2ll = (long long)k - (long long)s_below;
    const bool fast = (M0 <= CAP) && (r2ll >= 0) && (r2ll < (long long)M0);

    if (fast) {
        const unsigned r2 = (unsigned)r2ll;
        // fine histogram from LDS candidates (~9 elems/thread, 2048 bins)
        for (unsigned i = tid; i < M0; i += TPB) {
            float f = __uint_as_float(cand[i]);
            int b = (int)((f - BLO) * SCALE);
            b = b < 0 ? 0 : (b >= NB ? NB - 1 : b);
            atomicAdd(&hist[b], 1u);
        }
        __syncthreads();
        hist_select(hist, r2, tid, wsum, wbase, &s_bin, &s_cum);
        const int bin = s_bin;
        const unsigned r3 = r2 - s_cum;
        for (unsigned i = tid; i < M0; i += TPB) {
            unsigned u = cand[i];
            float f = __uint_as_float(u);
            int b = (int)((f - BLO) * SCALE);
            b = b < 0 ? 0 : (b >= NB ? NB - 1 : b);
            if (b == bin) { unsigned pp = atomicAdd(&s_tc, 1u); if (pp < TINY) tiny[pp] = u; }
        }
        __syncthreads();
        const unsigned c = s_tc;
        if (c > TINY) { if (tid == 0) s_fb = 1; }
        else if (tid < 64) {
            unsigned uj = (lane < (int)c) ? tiny[lane] : 0xFFFFFFFFu;
            unsigned less = 0, eq = 0;
            for (unsigned i2 = 0; i2 < c; ++i2) {
                unsigned ui = tiny[i2];
                less += (ui < uj) ? 1u : 0u;
                eq   += (ui == uj) ? 1u : 0u;
            }
            bool cond = (lane < (int)c) && (less <= r3) && (r3 < less + eq);
            unsigned long long cm = __ballot(cond);
            if (cond && lane == __ffsll((long long)cm) - 1)
                s_cut = __uint_as_float(uj);    // positive floats: raw bits monotone
        }
    } else {
        if (tid == 0) s_fb = 1;
    }
    __syncthreads();

    if (s_fb) {
        // ---- exact fallback over REGISTERS: 3-pass radix refinement (11/11/10) ----
        unsigned prefix = 0;
        unsigned rr = (unsigned)k;
        const int shifts[3] = {21, 10, 0};
        const int bitsc[3]  = {11, 11, 10};
        for (int pass = 0; pass < 3; ++pass) {
            const int sh = shifts[pass];
            const unsigned nbm = (1u << bitsc[pass]) - 1u;
            for (int i = tid; i < NB; i += TPB) hist[i] = 0u;
            __syncthreads();
            #pragma unroll
            for (int j = 0; j < F4PT; ++j) {
                const float vals[4] = {v[j].x, v[j].y, v[j].z, v[j].w};
                #pragma unroll
                for (int q = 0; q < 4; ++q) {
                    unsigned u = f2ord(vals[q]);
                    if (pass == 0 || (u >> (sh + bitsc[pass])) == prefix)
                        atomicAdd(&hist[(u >> sh) & nbm], 1u);
                }
            }
            __syncthreads();
            hist_select(hist, rr, tid, wsum, wbase, &s_bin, &s_cum);
            prefix = (prefix << bitsc[pass]) | (unsigned)s_bin;
            rr -= s_cum;
        }
        if (tid == 0) s_cut = ord2f(prefix);
        __syncthreads();
    }

    const float cut = s_cut;

    // ---- pass C: write relu(v - cut) straight from registers ----
    #pragma unroll
    for (int j = 0; j < F4PT; ++j) {
        float4 o;
        o.x = fmaxf(v[j].x - cut, 0.0f);
        o.y = fmaxf(v[j].y - cut, 0.0f);
        o.z = fmaxf(v[j].z - cut, 0.0f);
        o.w = fmaxf(v[j].w - cut, 0.0f);
        outv[tid + j * TPB] = o;
    }
}

extern "C" void kernel_launch(void* const* d_in, const int* in_sizes, int n_in,
                              void* d_out, int out_size, void* d_ws, size_t ws_size,
                              hipStream_t stream) {
    const float* in = (const float*)d_in[0];
    float* out = (float*)d_out;
    const int N = 65536;
    const int B = in_sizes[0] / N;                        // 1024
    const int k = (int)(((long long)N * 4) / 5);          // 52428

    xsrelu_fused<<<dim3(B), dim3(TPB), 0, stream>>>(in, out, N, k);
}